// Round 4
// baseline (459.840 us; speedup 1.0000x reference)
//
#include <hip/hip_runtime.h>

typedef unsigned short u16;
typedef unsigned int u32;
typedef _Float16 h16;
typedef __attribute__((ext_vector_type(2))) _Float16 half2v;
typedef __attribute__((ext_vector_type(8))) _Float16 half8;
typedef __attribute__((ext_vector_type(8))) unsigned short ushort8;
typedef __attribute__((ext_vector_type(4))) float f32x4;

#define NPAIRS 15625            // 500000 / 32: each block = 8 waves = 2 strips (M=32)
#define STRIPH 12032            // h16 per strip arena (24064 B); block total 48128 B

// Planar hi/lo layout: value (row r, col c) of buffer with stride S:
//   hi at base + r*S + c  (rows 0..15), lo at base + (16+r)*S + c.
#define AE1 0                   // 32 cols
#define SE1 40
#define AE2 1280                // 64 cols
#define SE2 72
#define ACT 3584                // 256 cols
#define SCT 264
#define AMR 3712                // MR (<=128 cols) ALIASED into CT cols [128:256)
#define SMR 264                 //   written only after all reads of that region

#define MFMA16(A,B,C) __builtin_amdgcn_mfma_f32_16x16x32_f16(A,B,C,0,0,0)

// light barrier: drain LDS ops only; global (B-prefetch) loads stay in flight
#define LBAR() asm volatile("s_waitcnt lgkmcnt(0)\n\ts_barrier" ::: "memory")

// ---------------- packed weight frag-pairs (f16 hi/lo, planar) ----------------
#define F_L0   0
#define F_L1   2
#define F_L2   4
#define F_L3   8
#define F_L4   24
#define F_L5   56
#define F_L6   120
#define F_L7   136
#define F_L8   144
#define F_L9   160
#define F_L10  164
#define F_L11  166
#define F_L12  170
#define NFRAG  172              // d_ws bytes: 172*1024*2 = 352256

__device__ __forceinline__ u16 hb(h16 h) { union { h16 h; u16 u; } v; v.h = h; return v.u; }

__global__ __launch_bounds__(256) void pack_w(
    const float* w0, const float* w1, const float* w2, const float* w3, const float* w4,
    const float* w5, const float* w6, const float* w7, const float* w8, const float* w9,
    const float* w10, const float* w11, const float* w12, u16* __restrict__ packed)
{
  const float* ws[13] = {w0,w1,w2,w3,w4,w5,w6,w7,w8,w9,w10,w11,w12};
  const int Ka[13]  = {16,32,32,64,128,256,128,64,128,64,32,64,32};
  const int KT[13]  = {1,1,1,2,4,8,4,2,4,2,1,2,1};
  const int CO[13]  = {32,32,64,128,128,128,64,64,64,32,32,32,32};
  const int FO[13]  = {F_L0,F_L1,F_L2,F_L3,F_L4,F_L5,F_L6,F_L7,F_L8,F_L9,F_L10,F_L11,F_L12};
  int g = blockIdx.x * 256 + threadIdx.x;
  int f = g >> 6, lane = g & 63;
  if (f >= NFRAG) return;
  int layer = 0;
#pragma unroll
  for (int i = 1; i < 13; ++i) if (f >= FO[i]) layer = i;
  int fl = f - FO[layer];
  int kt = fl % KT[layer];
  int ct = fl / KT[layer];
  int cout = CO[layer];
  int quad = lane >> 4;
  int col  = ct * 16 + (lane & 15);
  u16 thi[8], tlo[8];
#pragma unroll
  for (int j = 0; j < 8; ++j) {
    int k = kt * 32 + quad * 8 + j;
    float w = (k < Ka[layer]) ? ws[layer][k * cout + col] : 0.f;
    h16 h = (h16)w;
    h16 l = (h16)(w - (float)h);
    thi[j] = hb(h); tlo[j] = hb(l);
  }
  u16* dst = packed + ((size_t)f * 64 + lane) * 16;
  *(ushort8*)dst       = *(const ushort8*)thi;
  *(ushort8*)(dst + 8) = *(const ushort8*)tlo;
}

// ---------------- fused backbone ----------------

__device__ __forceinline__ void splitw(h16* dst, int idx, int dlo, float v) {
  h16 h = (h16)v;
  dst[idx]       = h;
  dst[idx + dlo] = (h16)(v - (float)h);
}

__device__ __forceinline__ float red2p(const h16* cat, int cs, int rr, int cc) {
  half2v hp = *reinterpret_cast<const half2v*>(cat + rr * cs + 2 * cc);
  half2v lp = *reinterpret_cast<const half2v*>(cat + (rr + 16) * cs + 2 * cc);
  return (float)hp.x + (float)hp.y + (float)lp.x + (float)lp.y;
}

// One wave-unit: 2 ct-tiles x ONE strip — A read once, reused for both cts.
// EPI 0: relu->LDS | 1: +pair-red(cat) | 2: ->global.  BAR=1: block barrier
// between all LDS reads and epilogue writes (MR/CT aliasing in S5).
template<int KT, int EPI, int BAR>
__device__ __forceinline__ void layer1(
    const h16* __restrict__ asrc, int as,
    const h16* __restrict__ wp, int foff, int ct0, int lane,
    half8 pbh, half8 pbl, half8 pbh2, half8 pbl2,
    h16* dst, int ds, int colb, const h16* cat, int cs,
    float* __restrict__ gout, int grow0)
{
  const int l15 = lane & 15, quad = lane >> 4;
  const int abase = l15 * as + quad * 8;
  const int alo = 16 * as;
  f32x4 acc0 = {0.f,0.f,0.f,0.f}, acc1 = {0.f,0.f,0.f,0.f};
#pragma unroll
  for (int kt = 0; kt < KT; ++kt) {
    const h16* p0 = asrc + abase + kt * 32;
    half8 ah = *(const half8*)p0;
    half8 al = *(const half8*)(p0 + alo);
    half8 b0h, b0l, b1h, b1l;
    if (kt == 0) { b0h = pbh; b0l = pbl; b1h = pbh2; b1l = pbl2; }
    else {
      const h16* f0 = wp + (((size_t)(foff + ct0 * KT + kt)) * 64 + lane) * 16;
      const h16* f1 = wp + (((size_t)(foff + (ct0 + 1) * KT + kt)) * 64 + lane) * 16;
      b0h = *(const half8*)f0; b0l = *(const half8*)(f0 + 8);
      b1h = *(const half8*)f1; b1l = *(const half8*)(f1 + 8);
    }
    acc0 = MFMA16(al, b0h, acc0); acc0 = MFMA16(ah, b0l, acc0); acc0 = MFMA16(ah, b0h, acc0);
    acc1 = MFMA16(al, b1h, acc1); acc1 = MFMA16(ah, b1l, acc1); acc1 = MFMA16(ah, b1h, acc1);
  }
  const int cc0 = ct0 * 16 + l15, cc1 = cc0 + 16;
  float v0r[4], v1r[4];
#pragma unroll
  for (int r = 0; r < 4; ++r) {
    const int rr = quad * 4 + r;
    float v0 = acc0[r] > 0.f ? acc0[r] : 0.f;
    float v1 = acc1[r] > 0.f ? acc1[r] : 0.f;
    if (EPI == 1) {
      v0 += red2p(cat, cs, rr, cc0);
      v1 += red2p(cat, cs, rr, cc1);
    }
    v0r[r] = v0; v1r[r] = v1;
  }
  if (BAR) LBAR();                 // all reads of aliased region done before any write
  if (EPI <= 1) {
    const int dlo = 16 * ds;
#pragma unroll
    for (int r = 0; r < 4; ++r) {
      const int rr = quad * 4 + r;
      splitw(dst, rr * ds + colb + cc0, dlo, v0r[r]);
      splitw(dst, rr * ds + colb + cc1, dlo, v1r[r]);
    }
  } else {
#pragma unroll
    for (int r = 0; r < 4; ++r) {
      const int rr = quad * 4 + r;
      gout[(size_t)(grow0 + rr) * 32 + cc0] = v0r[r];
      gout[(size_t)(grow0 + rr) * 32 + cc1] = v1r[r];
    }
  }
}

#define PFB(FOFF, CIDX, KT_)                                                        \
  do { const h16* _fp = wp + (((size_t)((FOFF) + (CIDX) * (KT_))) * 64 + lane) * 16; \
       pbh = *(const half8*)_fp; pbl = *(const half8*)(_fp + 8); } while (0)
#define PFB2(FOFF, CIDX, KT_)                                                       \
  do { const h16* _fp = wp + (((size_t)((FOFF) + (CIDX) * (KT_))) * 64 + lane) * 16; \
       pbh2 = *(const half8*)_fp; pbl2 = *(const half8*)(_fp + 8); } while (0)

__global__ __launch_bounds__(512, 6) void backbone(
    const float* __restrict__ feat, const h16* __restrict__ wp, float* __restrict__ out)
{
  __shared__ h16 lds[2 * STRIPH];  // 48128 B -> 3 blocks/CU
  const int lane = threadIdx.x & 63;
  const int wv   = threadIdx.x >> 6;     // 0..7
  const int l15 = lane & 15, quad = lane >> 4;
  const int row0 = blockIdx.x * 32;
  const int c2 = (wv >> 1) * 2;          // ct0 for (2ct,1strip) mapping
  h16* Sb8 = lds + (wv & 1) * STRIPH;    // strip base for 8-wave stages

  half8 pbh, pbl, pbh2, pbl2;

  // ---- S0: L0 (4 waves = 1ct x 1strip each): feat (K=16 pad 32) -> CT[:,0:32]
  if (wv < 4) {
    const int st = wv >> 1, ct = wv & 1;
    PFB(F_L0, ct, 1);
    h16 th[8] = {0,0,0,0,0,0,0,0}, tl[8] = {0,0,0,0,0,0,0,0};
    if (quad < 2) {
      const float* s = feat + (size_t)(row0 + st * 16 + l15) * 16 + quad * 8;
      f32x4 ua = *(const f32x4*)s, ub = *(const f32x4*)(s + 4);
#pragma unroll
      for (int j = 0; j < 4; ++j) {
        h16 h;
        h = (h16)ua[j]; th[j]   = h; tl[j]   = (h16)(ua[j] - (float)h);
        h = (h16)ub[j]; th[4+j] = h; tl[4+j] = (h16)(ub[j] - (float)h);
      }
    }
    half8 ah = *(const half8*)th, al = *(const half8*)tl;
    f32x4 a = {0.f,0.f,0.f,0.f};
    a = MFMA16(al, pbh, a); a = MFMA16(ah, pbl, a); a = MFMA16(ah, pbh, a);
    h16* dstS = lds + st * STRIPH + ACT;
    const int dlo = 16 * SCT;
#pragma unroll
    for (int r = 0; r < 4; ++r) {
      const int rr = quad * 4 + r;
      splitw(dstS, rr * SCT + ct * 16 + l15, dlo, a[r] > 0.f ? a[r] : 0.f);
    }
  }
  if (wv < 2) { PFB(F_L1, 0, 1); PFB2(F_L1, 1, 1); }
  LBAR();

  // ---- S1: L1 (2 units, waves 0-1, strip=wv): x0(CT[0:32]) -> E1
  if (wv < 2) {
    h16* Sb = lds + wv * STRIPH;
    layer1<1,0,0>(Sb + ACT, SCT, wp, F_L1, 0, lane, pbh,pbl,pbh2,pbl2,
                  Sb + AE1, SE1, 0, nullptr, 0, nullptr, 0);
  }
  if (wv < 4) { PFB(F_L2, c2, 1); PFB2(F_L2, c2 + 1, 1); }
  LBAR();

  // ---- S2: L2 (4 units, waves 0-3): e1(E1) -> E2
  if (wv < 4) {
    layer1<1,0,0>(Sb8 + AE1, SE1, wp, F_L2, c2, lane, pbh,pbl,pbh2,pbl2,
                  Sb8 + AE2, SE2, 0, nullptr, 0, nullptr, 0);
  }
  PFB(F_L3, c2, 2); PFB2(F_L3, c2 + 1, 2);
  LBAR();

  // ---- S3: L3 (8 units): e2(E2) -> CT[:,0:128]
  layer1<2,0,0>(Sb8 + AE2, SE2, wp, F_L3, c2, lane, pbh,pbl,pbh2,pbl2,
                Sb8 + ACT, SCT, 0, nullptr, 0, nullptr, 0);
  PFB(F_L4, c2, 4); PFB2(F_L4, c2 + 1, 4);
  LBAR();

  // ---- S4: L4 (8 units): e3(CT[0:128]) -> CT[:,128:256]
  layer1<4,0,0>(Sb8 + ACT, SCT, wp, F_L4, c2, lane, pbh,pbl,pbh2,pbl2,
                Sb8 + ACT, SCT, 128, nullptr, 0, nullptr, 0);
  PFB(F_L5, c2, 8); PFB2(F_L5, c2 + 1, 8);
  LBAR();

  // ---- S5: L5 (8 units): merge3(CT[0:256]) + red -> MR[:,0:128]  (MR aliases
  //         CT[128:256): mid-stage barrier inside layer1 orders reads before writes)
  layer1<8,1,1>(Sb8 + ACT, SCT, wp, F_L5, c2, lane, pbh,pbl,pbh2,pbl2,
                Sb8 + AMR, SMR, 0, Sb8 + ACT, SCT, nullptr, 0);
  if (wv < 4) { PFB(F_L6, c2, 4); PFB2(F_L6, c2 + 1, 4); }
  else        { const int w = wv - 4; PFB(F_L7, (w>>1)*2, 2); PFB2(F_L7, (w>>1)*2 + 1, 2); }
  LBAR();

  // ---- S6 (fused): L6 (4 units, waves 0-3): x2(MR[0:128]) -> CT[:,0:64]
  //                  L7 (4 units, waves 4-7): lat2(E2)      -> CT[:,64:128]
  if (wv < 4) {
    layer1<4,0,0>(Sb8 + AMR, SMR, wp, F_L6, c2, lane, pbh,pbl,pbh2,pbl2,
                  Sb8 + ACT, SCT, 0, nullptr, 0, nullptr, 0);
  } else {
    const int w = wv - 4;
    h16* Sb = lds + (w & 1) * STRIPH;
    layer1<2,0,0>(Sb + AE2, SE2, wp, F_L7, (w>>1)*2, lane, pbh,pbl,pbh2,pbl2,
                  Sb + ACT, SCT, 64, nullptr, 0, nullptr, 0);
  }
  if (wv < 4) { PFB(F_L8, c2, 4); PFB2(F_L8, c2 + 1, 4); }
  LBAR();

  // ---- S7: L8 (4 units, waves 0-3): merge2(CT[0:128]) + red -> MR[:,0:64]
  //         (writes CT cols [128:192): disjoint from reads)
  if (wv < 4) {
    layer1<4,1,0>(Sb8 + ACT, SCT, wp, F_L8, c2, lane, pbh,pbl,pbh2,pbl2,
                  Sb8 + AMR, SMR, 0, Sb8 + ACT, SCT, nullptr, 0);
  }
  if (wv < 2)      { PFB(F_L9, 0, 2);  PFB2(F_L9, 1, 2); }
  else if (wv < 4) { PFB(F_L10, 0, 1); PFB2(F_L10, 1, 1); }
  LBAR();

  // ---- S8 (fused): L9 (2 units, waves 0-1): x1(MR[0:64]) -> CT[:,0:32]
  //                  L10 (2 units, waves 2-3): lat1(E1)    -> CT[:,32:64]
  if (wv < 2) {
    h16* Sb = lds + wv * STRIPH;
    layer1<2,0,0>(Sb + AMR, SMR, wp, F_L9, 0, lane, pbh,pbl,pbh2,pbl2,
                  Sb + ACT, SCT, 0, nullptr, 0, nullptr, 0);
  } else if (wv < 4) {
    h16* Sb = lds + (wv - 2) * STRIPH;
    layer1<1,0,0>(Sb + AE1, SE1, wp, F_L10, 0, lane, pbh,pbl,pbh2,pbl2,
                  Sb + ACT, SCT, 32, nullptr, 0, nullptr, 0);
  }
  if (wv < 2) { PFB(F_L11, 0, 2); PFB2(F_L11, 1, 2); }
  LBAR();

  // ---- S9: L11 (2 units, waves 0-1): merge1(CT[0:64]) + red -> MR[:,0:32]
  //         (writes CT cols [128:160): disjoint from reads)
  if (wv < 2) {
    h16* Sb = lds + wv * STRIPH;
    layer1<2,1,0>(Sb + ACT, SCT, wp, F_L11, 0, lane, pbh,pbl,pbh2,pbl2,
                  Sb + AMR, SMR, 0, Sb + ACT, SCT, nullptr, 0);
    PFB(F_L12, 0, 1); PFB2(F_L12, 1, 1);
  }
  LBAR();

  // ---- S10: L12 (2 units, waves 0-1): out(MR[0:32]) -> global fp32 [N,32]
  if (wv < 2) {
    h16* Sb = lds + wv * STRIPH;
    layer1<1,2,0>(Sb + AMR, SMR, wp, F_L12, 0, lane, pbh,pbl,pbh2,pbl2,
                  nullptr, 0, 0, nullptr, 0, out, row0 + wv * 16);
  }
}

extern "C" void kernel_launch(void* const* d_in, const int* in_sizes, int n_in,
                              void* d_out, int out_size, void* d_ws, size_t ws_size,
                              hipStream_t stream) {
  (void)in_sizes; (void)n_in; (void)out_size; (void)ws_size;
  u16* packed = (u16*)d_ws;   // 352256 B

  // order: in, enc1, enc2, enc3, lat3, merge3, up3, lat2, merge2, up2, lat1, merge1, up1
  hipLaunchKernelGGL(pack_w, dim3(43), dim3(256), 0, stream,
      (const float*)d_in[2],  (const float*)d_in[3],  (const float*)d_in[4],
      (const float*)d_in[5],  (const float*)d_in[8],  (const float*)d_in[11],
      (const float*)d_in[14], (const float*)d_in[7],  (const float*)d_in[10],
      (const float*)d_in[13], (const float*)d_in[6],  (const float*)d_in[9],
      (const float*)d_in[12], packed);

  hipLaunchKernelGGL(backbone, dim3(NPAIRS), dim3(512), 0, stream,
                     (const float*)d_in[0], (const h16*)packed, (float*)d_out);
}

// Round 5
// 438.332 us; speedup vs baseline: 1.0491x; 1.0491x over previous
//
#include <hip/hip_runtime.h>

typedef unsigned short u16;
typedef unsigned int u32;
typedef _Float16 h16;
typedef __attribute__((ext_vector_type(2))) _Float16 half2v;
typedef __attribute__((ext_vector_type(8))) _Float16 half8;
typedef __attribute__((ext_vector_type(8))) unsigned short ushort8;
typedef __attribute__((ext_vector_type(4))) float f32x4;

#define NPAIRS 15625            // 500000 / 32: each block = 8 waves = 2 strips (M=32)
#define STRIPH 12032            // h16 per strip arena (24064 B); block total 48128 B

// Planar hi/lo layout + column-bit-4 XOR swizzle:
//   logical value (row r in [0,16) hi / +16 lo, col c) of a buffer with stride S
//   lives at  base + r*S + (c ^ ((r&8)<<1)).
// The swizzle spreads quad row-groups across banks: epilogue b16 writes and red
// b32 reads go from 4-way conflicts to uniform 2-way (free). A-frag b128 reads
// absorb the XOR into the chunk index (quad ^= (l15>>3)<<1) at zero runtime cost.
#define AE1 0                   // 32 cols
#define SE1 40
#define AE2 1280                // 64 cols
#define SE2 72
#define ACT 3584                // 256 cols
#define SCT 264
#define AMR 3712                // MR (<=128 cols) ALIASED into CT cols [128:256)
#define SMR 264                 //   written only after all reads of that region

#define MFMA16(A,B,C) __builtin_amdgcn_mfma_f32_16x16x32_f16(A,B,C,0,0,0)

// light barrier: drain LDS ops only; global (B-prefetch) loads stay in flight
#define LBAR() asm volatile("s_waitcnt lgkmcnt(0)\n\ts_barrier" ::: "memory")

// ---------------- packed weight frag-pairs (f16 hi/lo, planar) ----------------
#define F_L0   0
#define F_L1   2
#define F_L2   4
#define F_L3   8
#define F_L4   24
#define F_L5   56
#define F_L6   120
#define F_L7   136
#define F_L8   144
#define F_L9   160
#define F_L10  164
#define F_L11  166
#define F_L12  170
#define NFRAG  172              // d_ws bytes: 172*1024*2 = 352256

__device__ __forceinline__ u16 hb(h16 h) { union { h16 h; u16 u; } v; v.h = h; return v.u; }

__global__ __launch_bounds__(256) void pack_w(
    const float* w0, const float* w1, const float* w2, const float* w3, const float* w4,
    const float* w5, const float* w6, const float* w7, const float* w8, const float* w9,
    const float* w10, const float* w11, const float* w12, u16* __restrict__ packed)
{
  const float* ws[13] = {w0,w1,w2,w3,w4,w5,w6,w7,w8,w9,w10,w11,w12};
  const int Ka[13]  = {16,32,32,64,128,256,128,64,128,64,32,64,32};
  const int KT[13]  = {1,1,1,2,4,8,4,2,4,2,1,2,1};
  const int CO[13]  = {32,32,64,128,128,128,64,64,64,32,32,32,32};
  const int FO[13]  = {F_L0,F_L1,F_L2,F_L3,F_L4,F_L5,F_L6,F_L7,F_L8,F_L9,F_L10,F_L11,F_L12};
  int g = blockIdx.x * 256 + threadIdx.x;
  int f = g >> 6, lane = g & 63;
  if (f >= NFRAG) return;
  int layer = 0;
#pragma unroll
  for (int i = 1; i < 13; ++i) if (f >= FO[i]) layer = i;
  int fl = f - FO[layer];
  int kt = fl % KT[layer];
  int ct = fl / KT[layer];
  int cout = CO[layer];
  int quad = lane >> 4;
  int col  = ct * 16 + (lane & 15);
  u16 thi[8], tlo[8];
#pragma unroll
  for (int j = 0; j < 8; ++j) {
    int k = kt * 32 + quad * 8 + j;
    float w = (k < Ka[layer]) ? ws[layer][k * cout + col] : 0.f;
    h16 h = (h16)w;
    h16 l = (h16)(w - (float)h);
    thi[j] = hb(h); tlo[j] = hb(l);
  }
  u16* dst = packed + ((size_t)f * 64 + lane) * 16;
  *(ushort8*)dst       = *(const ushort8*)thi;
  *(ushort8*)(dst + 8) = *(const ushort8*)tlo;
}

// ---------------- fused backbone ----------------

__device__ __forceinline__ void splitw(h16* dst, int idx, int dlo, float v) {
  h16 h = (h16)v;
  dst[idx]       = h;
  dst[idx + dlo] = (h16)(v - (float)h);
}

// red pair-sum with pre-swizzled h16 column index ccr
__device__ __forceinline__ float red2s(const h16* cat, int cs, int rr, int ccr) {
  half2v hp = *reinterpret_cast<const half2v*>(cat + rr * cs + ccr);
  half2v lp = *reinterpret_cast<const half2v*>(cat + (rr + 16) * cs + ccr);
  return (float)hp.x + (float)hp.y + (float)lp.x + (float)lp.y;
}

// ---- 1 ct-tile x 2 strips (B loaded once; heavy encoder stages) ----
// EPI 0: relu->LDS | 1: +pair-red(cat) | 2: ->global.  BAR=1: block barrier
// between all LDS reads and epilogue writes (MR/CT aliasing in S5).
template<int KT, int EPI, int BAR>
__device__ __forceinline__ void layerW(
    const h16* __restrict__ asrc, int as,
    const h16* __restrict__ wp, int foff, int ct, int lane,
    half8 pbh, half8 pbl,
    h16* dst, int ds, int colb, const h16* cat, int cs,
    float* __restrict__ gout, int row0)
{
  const int l15 = lane & 15, quad = lane >> 4;
  const int qsw = quad ^ ((l15 >> 3) << 1);          // A-read chunk swizzle
  const int abase = l15 * as + qsw * 8;
  const int alo = 16 * as;
  f32x4 a0 = {0.f,0.f,0.f,0.f}, a1 = {0.f,0.f,0.f,0.f};
#pragma unroll
  for (int kt = 0; kt < KT; ++kt) {
    half8 bhv, blv;
    if (kt == 0) { bhv = pbh; blv = pbl; }
    else {
      const h16* fp = wp + (((size_t)(foff + ct * KT + kt)) * 64 + lane) * 16;
      bhv = *(const half8*)fp;
      blv = *(const half8*)(fp + 8);
    }
    const h16* p0 = asrc + abase + kt * 32;
    const h16* p1 = p0 + STRIPH;
    half8 ah0 = *(const half8*)p0;
    half8 al0 = *(const half8*)(p0 + alo);
    half8 ah1 = *(const half8*)p1;
    half8 al1 = *(const half8*)(p1 + alo);
    a0 = MFMA16(al0, bhv, a0); a0 = MFMA16(ah0, blv, a0); a0 = MFMA16(ah0, bhv, a0);
    a1 = MFMA16(al1, bhv, a1); a1 = MFMA16(ah1, blv, a1); a1 = MFMA16(ah1, bhv, a1);
  }
  const int csw = (quad & 2) << 3;                   // write/red col swizzle
  const int cc  = ct * 16 + l15;
  const int ccw = (colb + cc) ^ csw;
  const int ccr = (2 * cc) ^ csw;
  float v0r[4], v1r[4];
#pragma unroll
  for (int r = 0; r < 4; ++r) {
    const int rr = quad * 4 + r;
    float v0 = a0[r] > 0.f ? a0[r] : 0.f;
    float v1 = a1[r] > 0.f ? a1[r] : 0.f;
    if (EPI == 1) {
      v0 += red2s(cat, cs, rr, ccr);
      v1 += red2s(cat + STRIPH, cs, rr, ccr);
    }
    v0r[r] = v0; v1r[r] = v1;
  }
  if (BAR) LBAR();                 // all reads of aliased region done before any write
  if (EPI <= 1) {
    const int dlo = 16 * ds;
#pragma unroll
    for (int r = 0; r < 4; ++r) {
      const int rr = quad * 4 + r;
      splitw(dst,          rr * ds + ccw, dlo, v0r[r]);
      splitw(dst + STRIPH, rr * ds + ccw, dlo, v1r[r]);
    }
  } else {
#pragma unroll
    for (int r = 0; r < 4; ++r) {
      const int rr = quad * 4 + r;
      gout[(size_t)(row0 + rr) * 32 + cc]      = v0r[r];
      gout[(size_t)(row0 + 16 + rr) * 32 + cc] = v1r[r];
    }
  }
}

// ---- 1 ct-tile x 1 strip (light/decoder stages; 8-wave spreading) ----
template<int KT, int EPI, int BAR>
__device__ __forceinline__ void unitS(
    const h16* __restrict__ asrc, int as,
    const h16* __restrict__ wp, int foff, int ct, int lane,
    half8 pbh, half8 pbl,
    h16* dst, int ds, int colb, const h16* cat, int cs,
    float* __restrict__ gout, int grow0)
{
  const int l15 = lane & 15, quad = lane >> 4;
  const int qsw = quad ^ ((l15 >> 3) << 1);
  const int abase = l15 * as + qsw * 8;
  const int alo = 16 * as;
  f32x4 a = {0.f,0.f,0.f,0.f};
#pragma unroll
  for (int kt = 0; kt < KT; ++kt) {
    half8 bhv, blv;
    if (kt == 0) { bhv = pbh; blv = pbl; }
    else {
      const h16* fp = wp + (((size_t)(foff + ct * KT + kt)) * 64 + lane) * 16;
      bhv = *(const half8*)fp;
      blv = *(const half8*)(fp + 8);
    }
    const h16* p0 = asrc + abase + kt * 32;
    half8 ah = *(const half8*)p0;
    half8 al = *(const half8*)(p0 + alo);
    a = MFMA16(al, bhv, a); a = MFMA16(ah, blv, a); a = MFMA16(ah, bhv, a);
  }
  const int csw = (quad & 2) << 3;
  const int cc  = ct * 16 + l15;
  const int ccw = (colb + cc) ^ csw;
  const int ccr = (2 * cc) ^ csw;
  float vr[4];
#pragma unroll
  for (int r = 0; r < 4; ++r) {
    const int rr = quad * 4 + r;
    float v = a[r] > 0.f ? a[r] : 0.f;
    if (EPI == 1) v += red2s(cat, cs, rr, ccr);
    vr[r] = v;
  }
  if (BAR) LBAR();
  if (EPI <= 1) {
    const int dlo = 16 * ds;
#pragma unroll
    for (int r = 0; r < 4; ++r) {
      const int rr = quad * 4 + r;
      splitw(dst, rr * ds + ccw, dlo, vr[r]);
    }
  } else {
#pragma unroll
    for (int r = 0; r < 4; ++r) {
      const int rr = quad * 4 + r;
      gout[(size_t)(grow0 + rr) * 32 + cc] = vr[r];
    }
  }
}

#define PFB(FOFF, CIDX, KT_)                                                        \
  do { const h16* _fp = wp + (((size_t)((FOFF) + (CIDX) * (KT_))) * 64 + lane) * 16; \
       pbh = *(const half8*)_fp; pbl = *(const half8*)(_fp + 8); } while (0)
#define PFB2(FOFF, CIDX, KT_)                                                       \
  do { const h16* _fp = wp + (((size_t)((FOFF) + (CIDX) * (KT_))) * 64 + lane) * 16; \
       pbh2 = *(const half8*)_fp; pbl2 = *(const half8*)(_fp + 8); } while (0)

__global__ __launch_bounds__(512, 6) void backbone(
    const float* __restrict__ feat, const h16* __restrict__ wp, float* __restrict__ out)
{
  __shared__ h16 lds[2 * STRIPH];  // 48128 B -> 3 blocks/CU
  const int lane = threadIdx.x & 63;
  const int wv   = threadIdx.x >> 6;     // 0..7
  const int l15 = lane & 15, quad = lane >> 4;
  const int row0 = blockIdx.x * 32;

  h16* E1 = lds + AE1;
  h16* E2 = lds + AE2;
  h16* CT = lds + ACT;
  h16* MR = lds + AMR;

  half8 pbh, pbl, pbh2, pbl2;

  // ---- S0: L0 (4 waves = 1ct x 1strip): feat (K=16 pad 32) -> CT[:,0:32]
  if (wv < 4) {
    const int s = wv >> 1, c = wv & 1;
    PFB(F_L0, c, 1);
    h16 th[8] = {0,0,0,0,0,0,0,0}, tl[8] = {0,0,0,0,0,0,0,0};
    if (quad < 2) {
      const float* sp = feat + (size_t)(row0 + s * 16 + l15) * 16 + quad * 8;
      f32x4 ua = *(const f32x4*)sp, ub = *(const f32x4*)(sp + 4);
#pragma unroll
      for (int j = 0; j < 4; ++j) {
        h16 h;
        h = (h16)ua[j]; th[j]   = h; tl[j]   = (h16)(ua[j] - (float)h);
        h = (h16)ub[j]; th[4+j] = h; tl[4+j] = (h16)(ub[j] - (float)h);
      }
    }
    half8 ah = *(const half8*)th, al = *(const half8*)tl;
    f32x4 a = {0.f,0.f,0.f,0.f};
    a = MFMA16(al, pbh, a); a = MFMA16(ah, pbl, a); a = MFMA16(ah, pbh, a);
    h16* dstS = lds + s * STRIPH + ACT;
    const int csw = (quad & 2) << 3;
    const int ccw = (c * 16 + l15) ^ csw;
    const int dlo = 16 * SCT;
#pragma unroll
    for (int r = 0; r < 4; ++r) {
      const int rr = quad * 4 + r;
      splitw(dstS, rr * SCT + ccw, dlo, a[r] > 0.f ? a[r] : 0.f);
    }
    PFB(F_L1, c, 1);
  }
  LBAR();

  // ---- S1: L1 (4 units = 2ct x 2strips): x0(CT[0:32]) -> E1
  if (wv < 4) {
    const int s = wv >> 1, c = wv & 1;
    h16* Sb = lds + s * STRIPH;
    unitS<1,0,0>(Sb + ACT, SCT, wp, F_L1, c, lane, pbh, pbl,
                 Sb + AE1, SE1, 0, nullptr, 0, nullptr, 0);
  }
  PFB(F_L2, wv & 3, 1);
  LBAR();

  // ---- S2: L2 (8 units = 4ct x 2strips): e1(E1) -> E2
  {
    const int s = wv >> 2, c = wv & 3;
    h16* Sb = lds + s * STRIPH;
    unitS<1,0,0>(Sb + AE1, SE1, wp, F_L2, c, lane, pbh, pbl,
                 Sb + AE2, SE2, 0, nullptr, 0, nullptr, 0);
  }
  PFB(F_L3, wv, 2);
  LBAR();

  // ---- S3: L3 (8 waves, 1ct x 2strips, B 1x): e2(E2) -> CT[:,0:128]
  layerW<2,0,0>(E2, SE2, wp, F_L3, wv, lane, pbh, pbl, CT, SCT, 0, nullptr, 0, nullptr, 0);
  PFB(F_L4, wv, 4);
  LBAR();

  // ---- S4: L4 (8 waves): e3(CT[0:128]) -> CT[:,128:256]
  layerW<4,0,0>(CT, SCT, wp, F_L4, wv, lane, pbh, pbl, CT, SCT, 128, nullptr, 0, nullptr, 0);
  PFB(F_L5, wv, 8);
  LBAR();

  // ---- S5: L5 (8 waves): merge3(CT[0:256]) + red -> MR[:,0:128]  (MR aliases
  //         CT[128:256): mid-stage barrier inside layerW orders reads before writes)
  layerW<8,1,1>(CT, SCT, wp, F_L5, wv, lane, pbh, pbl, MR, SMR, 0, CT, SCT, nullptr, 0);
  PFB (F_L6, wv & 3, 4);
  PFB2(F_L7, wv & 3, 2);
  LBAR();

  // ---- S6: per wave: L6 unit (x2(MR[0:128]) -> CT[:,0:64]) then
  //                    L7 unit (lat2(E2)      -> CT[:,64:128])   [8 waves, balanced]
  {
    const int s = wv >> 2, c = wv & 3;
    h16* Sb = lds + s * STRIPH;
    unitS<4,0,0>(Sb + AMR, SMR, wp, F_L6, c, lane, pbh,  pbl,
                 Sb + ACT, SCT, 0,  nullptr, 0, nullptr, 0);
    unitS<2,0,0>(Sb + AE2, SE2, wp, F_L7, c, lane, pbh2, pbl2,
                 Sb + ACT, SCT, 64, nullptr, 0, nullptr, 0);
  }
  PFB(F_L8, wv & 3, 4);
  LBAR();

  // ---- S7: L8 (8 units = 4ct x 2strips): merge2(CT[0:128]) + red -> MR[:,0:64]
  //         (writes CT cols [128:192): disjoint from reads)
  {
    const int s = wv >> 2, c = wv & 3;
    h16* Sb = lds + s * STRIPH;
    unitS<4,1,0>(Sb + ACT, SCT, wp, F_L8, c, lane, pbh, pbl,
                 Sb + AMR, SMR, 0, Sb + ACT, SCT, nullptr, 0);
  }
  if (wv < 4) PFB(F_L9, wv & 1, 2); else PFB(F_L10, (wv - 4) & 1, 1);
  LBAR();

  // ---- S8: L9 (4 units, waves 0-3): x1(MR[0:64]) -> CT[:,0:32]
  //          L10 (4 units, waves 4-7): lat1(E1)    -> CT[:,32:64]
  if (wv < 4) {
    const int s = wv >> 1, c = wv & 1;
    h16* Sb = lds + s * STRIPH;
    unitS<2,0,0>(Sb + AMR, SMR, wp, F_L9, c, lane, pbh, pbl,
                 Sb + ACT, SCT, 0, nullptr, 0, nullptr, 0);
  } else {
    const int w = wv - 4, s = w >> 1, c = w & 1;
    h16* Sb = lds + s * STRIPH;
    unitS<1,0,0>(Sb + AE1, SE1, wp, F_L10, c, lane, pbh, pbl,
                 Sb + ACT, SCT, 32, nullptr, 0, nullptr, 0);
  }
  if (wv < 4) PFB(F_L11, wv & 1, 2);
  LBAR();

  // ---- S9: L11 (4 units, waves 0-3): merge1(CT[0:64]) + red -> MR[:,0:32]
  //         (writes CT cols [128:160): disjoint from reads)
  if (wv < 4) {
    const int s = wv >> 1, c = wv & 1;
    h16* Sb = lds + s * STRIPH;
    unitS<2,1,0>(Sb + ACT, SCT, wp, F_L11, c, lane, pbh, pbl,
                 Sb + AMR, SMR, 0, Sb + ACT, SCT, nullptr, 0);
    PFB(F_L12, c, 1);
  }
  LBAR();

  // ---- S10: L12 (4 units, waves 0-3): out(MR[0:32]) -> global fp32 [N,32]
  if (wv < 4) {
    const int s = wv >> 1, c = wv & 1;
    h16* Sb = lds + s * STRIPH;
    unitS<1,2,0>(Sb + AMR, SMR, wp, F_L12, c, lane, pbh, pbl,
                 nullptr, 0, 0, nullptr, 0, out, row0 + s * 16);
  }
}

extern "C" void kernel_launch(void* const* d_in, const int* in_sizes, int n_in,
                              void* d_out, int out_size, void* d_ws, size_t ws_size,
                              hipStream_t stream) {
  (void)in_sizes; (void)n_in; (void)out_size; (void)ws_size;
  u16* packed = (u16*)d_ws;   // 352256 B

  // order: in, enc1, enc2, enc3, lat3, merge3, up3, lat2, merge2, up2, lat1, merge1, up1
  hipLaunchKernelGGL(pack_w, dim3(43), dim3(256), 0, stream,
      (const float*)d_in[2],  (const float*)d_in[3],  (const float*)d_in[4],
      (const float*)d_in[5],  (const float*)d_in[8],  (const float*)d_in[11],
      (const float*)d_in[14], (const float*)d_in[7],  (const float*)d_in[10],
      (const float*)d_in[13], (const float*)d_in[6],  (const float*)d_in[9],
      (const float*)d_in[12], packed);

  hipLaunchKernelGGL(backbone, dim3(NPAIRS), dim3(512), 0, stream,
                     (const float*)d_in[0], (const h16*)packed, (float*)d_out);
}